// Round 4
// baseline (632.311 us; speedup 1.0000x reference)
//
#include <hip/hip_runtime.h>
#include <math.h>

// Problem constants
#define S_LEN 2048
#define HID 4096
#define NH 32
#define NKV 8
#define HD 128
#define QKV_N ((NH + 2*NKV) * HD)   // 6144
#define NQK (NH + NKV)              // 40
static __device__ __constant__ const float SCALE_F = 0.08838834764831845f; // 128^-0.5

typedef __bf16 bf16x8 __attribute__((ext_vector_type(8)));
typedef __bf16 bf16x4 __attribute__((ext_vector_type(4)));
typedef float  f32x4  __attribute__((ext_vector_type(4)));

#define GLD_LDS(gptr, lptr) \
  __builtin_amdgcn_global_load_lds( \
      (const __attribute__((address_space(1))) uint32_t*)(gptr), \
      (__attribute__((address_space(3))) uint32_t*)(lptr), 16, 0, 0)

// ---------- cast fp32 -> bf16 (vectorized) ----------
__global__ void cast_bf16_kernel(const float4* __restrict__ in, __bf16* __restrict__ out, int n4) {
  int i = blockIdx.x * blockDim.x + threadIdx.x;
  if (i >= n4) return;
  float4 v = in[i];
  bf16x4 o = { (__bf16)v.x, (__bf16)v.y, (__bf16)v.z, (__bf16)v.w };
  *(bf16x4*)(out + (size_t)i * 4) = o;
}

// ---------- transpose + cast: in[R][C] fp32 -> out[C][R] bf16 ----------
__global__ void transpose_cast_kernel(const float* __restrict__ in, __bf16* __restrict__ out,
                                      int R, int C) {
  __shared__ float tile[32][33];
  int bx = blockIdx.x * 32;  // col of in
  int by = blockIdx.y * 32;  // row of in
  int tx = threadIdx.x, ty = threadIdx.y;
  for (int i = 0; i < 32; i += 8)
    tile[ty + i][tx] = in[(size_t)(by + ty + i) * C + bx + tx];
  __syncthreads();
  for (int i = 0; i < 32; i += 8)
    out[(size_t)(bx + ty + i) * R + by + tx] = (__bf16)tile[tx][ty + i];
}

// ---------- V transpose: Vt[kvh][d][s] = qkv[s][(NH+NKV)*HD + kvh*HD + d] ----------
__global__ void transpose_v_kernel(const __bf16* __restrict__ qkv, __bf16* __restrict__ Vt) {
  __shared__ __bf16 tile[32][33];
  int kvh = blockIdx.z;
  int sb = blockIdx.x * 32;
  int db = blockIdx.y * 32;
  int tx = threadIdx.x, ty = threadIdx.y;
  const __bf16* src = qkv + (size_t)(NH + NKV) * HD + (size_t)kvh * HD;
  for (int i = 0; i < 32; i += 8)
    tile[ty + i][tx] = src[(size_t)(sb + ty + i) * QKV_N + db + tx];
  __syncthreads();
  for (int i = 0; i < 32; i += 8)
    Vt[((size_t)kvh * HD + db + ty + i) * S_LEN + sb + tx] = tile[tx][ty + i];
}

// ---------- RoPE: split qkv -> Qr [S][NH][HD], Kr [S][NKV][HD] with rotation ----------
__global__ void rope_kernel(const __bf16* __restrict__ qkv, const int* __restrict__ pos,
                            __bf16* __restrict__ Qr, __bf16* __restrict__ Kr) {
  int idx = blockIdx.x * blockDim.x + threadIdx.x;
  int half = idx & 63;         // 0..63
  int t = idx >> 6;
  int hh = t % NQK;
  int s = t / NQK;
  if (s >= S_LEN) return;
  float p = (float)pos[s];
  float inv_freq = exp2f((float)half * -0.2076205059304601f); // 10000^(-half/64)
  float ang = p * inv_freq;
  float cs = cosf(ang), sn = sinf(ang);
  const __bf16* src; __bf16* dst;
  if (hh < NH) {
    src = qkv + (size_t)s * QKV_N + (size_t)hh * HD;
    dst = Qr + ((size_t)s * NH + hh) * HD;
  } else {
    int kh = hh - NH;
    src = qkv + (size_t)s * QKV_N + (size_t)NH * HD + (size_t)kh * HD;
    dst = Kr + ((size_t)s * NKV + kh) * HD;
  }
  float x1 = (float)src[half], x2 = (float)src[half + 64];
  dst[half]      = (__bf16)(x1 * cs - x2 * sn);
  dst[half + 64] = (__bf16)(x2 * cs + x1 * sn);
}

// ---------- bf16 MFMA GEMM: C[M][N] = A[M][K] @ Bt[N][K]^T ----------
// m97 structure + two new levers:
//  1) global-side k-chunk swizzle (kg = kc ^ ((row>>1)&3)) so fragment ds_read_b128
//     hits 8 bank-groups x 2 lanes (free) instead of 2 groups x 8 (2.9x serialized).
//     LDS dst stays linear (global_load_lds constraint); global stays within-segment
//     permuted (coalescing unchanged). Read side compensates: slot = quad ^ ((l16>>1)&3).
//  2) C^T accumulation (operand swap, fragment layouts symmetric) -> each lane holds 4
//     consecutive output COLS; epilogue round-trips per-wave LDS scratch (stride 68,
//     conflict-free) for 16B/8B coalesced stores instead of 64 scattered 2B/4B stores.
template <typename OutT>
__global__ __launch_bounds__(256) void gemm_bt_kernel(const __bf16* __restrict__ A,
                                                      const __bf16* __restrict__ Bt,
                                                      OutT* __restrict__ C,
                                                      int M, int N, int K) {
  __shared__ __align__(16) char smem[34816];   // As(8K)+Bs(8K); epilogue: 4 x 8704B scratch
  __bf16* As = (__bf16*)smem;
  __bf16* Bs = (__bf16*)(smem + 8192);
  const int tid = threadIdx.x;
  const int lane = tid & 63;
  const int wave = tid >> 6;
  const int quad = lane >> 4;
  const int l16 = lane & 15;
  const int wm = (wave >> 1) * 64;
  const int wn = (wave & 1) * 64;
  const size_t bm = (size_t)blockIdx.y * 128;
  const size_t bn = (size_t)blockIdx.x * 128;
  const int sxl = quad ^ ((l16 >> 1) & 3);   // swizzled chunk slot for fragment reads

  f32x4 acc[4][4] = {};

  for (int k0 = 0; k0 < K; k0 += 32) {
    for (int it = 0; it < 2; ++it) {
      int c = it * 256 + tid;          // chunk 0..511, 16B each (linear LDS dst)
      int row = c >> 2, kc = c & 3;
      int kg = kc ^ ((row >> 1) & 3);  // swizzled global k-chunk
      GLD_LDS(&A[(bm + row) * (size_t)K + k0 + kg * 8], &As[c * 8]);
      GLD_LDS(&Bt[(bn + row) * (size_t)K + k0 + kg * 8], &Bs[c * 8]);
    }
    __syncthreads();
    bf16x8 af[4], bfr[4];
    for (int i = 0; i < 4; ++i) af[i]  = *(const bf16x8*)&As[(wm + i * 16 + l16) * 32 + sxl * 8];
    for (int j = 0; j < 4; ++j) bfr[j] = *(const bf16x8*)&Bs[(wn + j * 16 + l16) * 32 + sxl * 8];
    for (int i = 0; i < 4; ++i)
      for (int j = 0; j < 4; ++j)   // C^T: A-op = B-frag, B-op = A-frag
        acc[i][j] = __builtin_amdgcn_mfma_f32_16x16x32_bf16(bfr[j], af[i], acc[i][j], 0, 0, 0);
    __syncthreads();
  }

  // acc[i][j][r] = C(row = bm+wm+i*16+l16, col = bn+wn+j*16+quad*4+r)
  // Two passes of 32 rows through per-wave f32 scratch (stride 68: conflict-free).
  float* scr = (float*)(smem + wave * 8704);
  for (int p = 0; p < 2; ++p) {
    for (int i2 = 0; i2 < 2; ++i2)
      for (int j = 0; j < 4; ++j)
        *(f32x4*)&scr[(i2 * 16 + l16) * 68 + j * 16 + quad * 4] = acc[p * 2 + i2][j];
    // same-wave readback (LDS in-order per wave; scratch is wave-private)
    for (int it = 0; it < 8; ++it) {
      int c = it * 64 + lane;
      int srow = c >> 4, ch = c & 15;
      f32x4 v = *(const f32x4*)&scr[srow * 68 + ch * 4];
      size_t row = bm + wm + p * 32 + srow;
      size_t col = bn + wn + ch * 4;
      if constexpr (sizeof(OutT) == 4) {
        *(f32x4*)&C[row * (size_t)N + col] = v;
      } else {
        bf16x4 o = { (__bf16)v[0], (__bf16)v[1], (__bf16)v[2], (__bf16)v[3] };
        *(bf16x4*)&C[row * (size_t)N + col] = o;
      }
    }
  }
}

// ---------- flash attention v3 (causal, GQA) ----------
// Transposed-scores formulation: sc = MFMA(K-frag, Q-frag) -> row=key, col=q(=l16).
// Softmax row-reduction = in-lane tree over 16 regs + 2 quad shuffles.
// PV: O^T = V^T · P^T. Epilogue transposes O^T through per-wave LDS scratch.
// LDS: unpadded Ks(16K)+Vs(16K)+Ps(8K) = 40960 B -> exactly 4 blocks/CU.
__global__ __launch_bounds__(256, 4) void attn_kernel(const __bf16* __restrict__ Qr,
                                                      const __bf16* __restrict__ Kr,
                                                      const __bf16* __restrict__ Vt,
                                                      __bf16* __restrict__ O) {
  __shared__ __align__(16) char smem[40960];
  __bf16* Ks = (__bf16*)smem;              // [64 key][128 d], 16B chunks swizzled
  __bf16* Vs = (__bf16*)(smem + 16384);    // [128 d][64 key], swizzled
  __bf16* Ps = (__bf16*)(smem + 32768);    // [4 wave][16 q][64 key], swizzled

  const int bid = blockIdx.x;
  const int h = bid & (NH - 1);
  const int qb = (S_LEN / 64 - 1) - (bid >> 5);     // longest first
  const int kvh = h >> 2;                            // REP = 4
  const int tid = threadIdx.x;
  const int lane = tid & 63, wave = tid >> 6;
  const int quad = lane >> 4, l16 = lane & 15;
  const int sw = l16 & 7;                            // swizzle key
  const int q0 = qb * 64;

  bf16x8 qf[4];
  {
    const __bf16* qp = Qr + (size_t)(q0 + wave * 16 + l16) * (NH * HD) + (size_t)h * HD + quad * 8;
    for (int kk = 0; kk < 4; ++kk) qf[kk] = *(const bf16x8*)(qp + kk * 32);
  }
  f32x4 oacc[8] = {};          // O^T: row=d_local(quad*4+r), col=q(l16)
  float m2 = -INFINITY, l_i = 0.0f;   // per-q state (q = l16), base-2 domain
  const float C2 = SCALE_F * 1.4426950408889634f;

  for (int kb = 0; kb <= q0; kb += 64) {
    for (int pass = 0; pass < 4; ++pass) {
      int c = pass * 256 + tid;
      int row = c >> 4, ch = c & 15;
      int chs = ch ^ (row & 7);
      *(uint4*)&Ks[row * 128 + chs * 8] =
        *(const uint4*)&Kr[(size_t)(kb + row) * (NKV * HD) + (size_t)kvh * HD + ch * 8];
    }
    for (int pass = 0; pass < 4; ++pass) {
      int c = pass * 256 + tid;
      int d = c >> 3, ch = c & 7;
      int chs = ch ^ (d & 7);
      *(uint4*)&Vs[d * 64 + chs * 8] =
        *(const uint4*)&Vt[((size_t)kvh * HD + d) * S_LEN + kb + ch * 8];
    }
    __syncthreads();

    f32x4 sc[4] = {};
    for (int jt = 0; jt < 4; ++jt)
      for (int kk = 0; kk < 4; ++kk) {
        bf16x8 kf = *(const bf16x8*)&Ks[(jt * 16 + l16) * 128 + ((kk * 4 + quad) ^ sw) * 8];
        sc[jt] = __builtin_amdgcn_mfma_f32_16x16x32_bf16(kf, qf[kk], sc[jt], 0, 0, 0);
      }

    float s[16];
    for (int jt = 0; jt < 4; ++jt)
      for (int r = 0; r < 4; ++r) s[jt * 4 + r] = sc[jt][r];
    if (kb == q0) {                      // diagonal tile: mask key > q
      int qloc = wave * 16 + l16;
      for (int jt = 0; jt < 4; ++jt)
        for (int r = 0; r < 4; ++r)
          if (jt * 16 + quad * 4 + r > qloc) s[jt * 4 + r] = -INFINITY;
    }
    float mx = s[0];
    for (int i = 1; i < 16; ++i) mx = fmaxf(mx, s[i]);
    mx = fmaxf(mx, __shfl_xor(mx, 16, 64));
    mx = fmaxf(mx, __shfl_xor(mx, 32, 64));
    float m2new = fmaxf(m2, mx * C2);
    float alpha = exp2f(m2 - m2new);
    float pv[16], sum = 0.0f;
    for (int i = 0; i < 16; ++i) { pv[i] = exp2f(fmaf(s[i], C2, -m2new)); sum += pv[i]; }
    sum += __shfl_xor(sum, 16, 64);
    sum += __shfl_xor(sum, 32, 64);
    l_i = l_i * alpha + sum;
    m2 = m2new;
    for (int dt = 0; dt < 8; ++dt) oacc[dt] *= alpha;

    __bf16* pw = Ps + wave * 1024 + l16 * 64;
    for (int jt = 0; jt < 4; ++jt) {
      bf16x4 pk = { (__bf16)pv[jt*4+0], (__bf16)pv[jt*4+1], (__bf16)pv[jt*4+2], (__bf16)pv[jt*4+3] };
      int chunk = jt * 2 + (quad >> 1);
      *(bf16x4*)&pw[((chunk ^ sw) * 8) + (quad & 1) * 4] = pk;
    }
    for (int half = 0; half < 2; ++half) {
      bf16x8 pf = *(const bf16x8*)&pw[((half * 4 + quad) ^ sw) * 8];
      for (int dt = 0; dt < 8; ++dt) {
        bf16x8 vf = *(const bf16x8*)&Vs[(dt * 16 + l16) * 64 + ((half * 4 + quad) ^ sw) * 8];
        oacc[dt] = __builtin_amdgcn_mfma_f32_16x16x32_bf16(vf, pf, oacc[dt], 0, 0, 0);
      }
    }
    __syncthreads();
  }

  float* scr = (float*)smem + wave * 2112;          // 16 q rows x 132 floats
  float inv = 1.0f / l_i;
  for (int dt = 0; dt < 8; ++dt) {
    f32x4 v = oacc[dt] * inv;
    *(f32x4*)&scr[l16 * 132 + dt * 16 + quad * 4] = v;
  }
  for (int it = 0; it < 4; ++it) {
    int c = it * 64 + lane;
    int row = c >> 4, ch = c & 15;
    const float* sp = &scr[row * 132 + ch * 8];
    f32x4 a = *(const f32x4*)sp;
    f32x4 b = *(const f32x4*)(sp + 4);
    bf16x8 o = { (__bf16)a[0], (__bf16)a[1], (__bf16)a[2], (__bf16)a[3],
                 (__bf16)b[0], (__bf16)b[1], (__bf16)b[2], (__bf16)b[3] };
    *(bf16x8*)&O[(size_t)(q0 + wave * 16 + row) * (NH * HD) + (size_t)h * HD + ch * 8] = o;
  }
}

extern "C" void kernel_launch(void* const* d_in, const int* in_sizes, int n_in,
                              void* d_out, int out_size, void* d_ws, size_t ws_size,
                              hipStream_t stream) {
  const float* hidden    = (const float*)d_in[0];
  const int*   positions = (const int*)d_in[1];
  const float* Wqkv      = (const float*)d_in[2];
  const float* Wo        = (const float*)d_in[3];
  float* out = (float*)d_out;

  char* p = (char*)d_ws;
  auto alloc = [&](size_t bytes) { char* r = p; p += (bytes + 255) & ~(size_t)255; return r; };
  __bf16* hid_bf = (__bf16*)alloc((size_t)S_LEN * HID * 2);       // 16 MB (reused as attn_out)
  __bf16* wqkvT  = (__bf16*)alloc((size_t)QKV_N * HID * 2);       // 48 MB  [6144][4096]
  __bf16* woT    = (__bf16*)alloc((size_t)HID * HID * 2);         // 32 MB  [4096][4096]
  __bf16* qkv    = (__bf16*)alloc((size_t)S_LEN * QKV_N * 2);     // 24 MB
  __bf16* Qr     = (__bf16*)alloc((size_t)S_LEN * NH * HD * 2);   // 16 MB
  __bf16* Kr     = (__bf16*)alloc((size_t)S_LEN * NKV * HD * 2);  // 4 MB
  __bf16* Vt     = (__bf16*)alloc((size_t)S_LEN * NKV * HD * 2);  // 4 MB
  __bf16* attn   = hid_bf;  // hidden_bf16 dead after GEMM1

  {
    int n4 = S_LEN * HID / 4;
    cast_bf16_kernel<<<(n4 + 255) / 256, 256, 0, stream>>>((const float4*)hidden, hid_bf, n4);
  }
  transpose_cast_kernel<<<dim3(QKV_N / 32, HID / 32), dim3(32, 8), 0, stream>>>(Wqkv, wqkvT, HID, QKV_N);
  transpose_cast_kernel<<<dim3(HID / 32, HID / 32), dim3(32, 8), 0, stream>>>(Wo, woT, HID, HID);
  gemm_bt_kernel<__bf16><<<dim3(QKV_N / 128, S_LEN / 128), 256, 0, stream>>>(
      hid_bf, wqkvT, qkv, S_LEN, QKV_N, HID);
  {
    int total = S_LEN * NQK * 64;
    rope_kernel<<<total / 256, 256, 0, stream>>>(qkv, positions, Qr, Kr);
  }
  transpose_v_kernel<<<dim3(S_LEN / 32, HD / 32, NKV), dim3(32, 8), 0, stream>>>(qkv, Vt);
  attn_kernel<<<NH * (S_LEN / 64), 256, 0, stream>>>(Qr, Kr, Vt, attn);
  gemm_bt_kernel<float><<<dim3(HID / 128, S_LEN / 128), 256, 0, stream>>>(
      attn, woT, out, S_LEN, HID, HID);
}